// Round 1
// baseline (112.378 us; speedup 1.0000x reference)
//
#include <hip/hip_runtime.h>
#include <hip/hip_bf16.h>

typedef unsigned short u16;
typedef __bf16 bf16x8 __attribute__((ext_vector_type(8)));
typedef float f32x4 __attribute__((ext_vector_type(4)));

#define NROW 8192
#define NHALF 4096
#define DIM 256
#define TILES 64                       // 8192 / 128
#define NBLK (TILES * (TILES + 1) / 2) // 2080 upper-triangular tiles

static __device__ __forceinline__ float fast_exp2(float x) {
#if __has_builtin(__builtin_amdgcn_exp2f)
  return __builtin_amdgcn_exp2f(x);
#else
  return exp2f(x);
#endif
}

static __device__ __forceinline__ u16 f2b(float x) {
  __hip_bfloat16 h = __float2bfloat16(x); // RNE
  u16 u;
  __builtin_memcpy(&u, &h, 2);
  return u;
}

// ---------------- K1: fp32 -> bf16 convert + per-row sum of squares ---------
// 2048 blocks x 256 threads; one wave per row (64 lanes x float4 = 256 elems).
__global__ void k_prep(const float* __restrict__ src, const float* __restrict__ tgt,
                       u16* __restrict__ Xb, float* __restrict__ sq) {
  int w = threadIdx.x >> 6, lane = threadIdx.x & 63;
  int row = blockIdx.x * 4 + w;
  const float* p = (row < NHALF) ? (src + (size_t)row * DIM)
                                 : (tgt + (size_t)(row - NHALF) * DIM);
  float4 v = *(const float4*)(p + lane * 4);
  ushort4 uv = make_ushort4(f2b(v.x), f2b(v.y), f2b(v.z), f2b(v.w));
  *(ushort4*)(Xb + (size_t)row * DIM + lane * 4) = uv;
  float s = v.x * v.x + v.y * v.y + v.z * v.z + v.w * v.w;
#pragma unroll
  for (int off = 32; off > 0; off >>= 1) s += __shfl_down(s, off);
  if (lane == 0) sq[row] = s;
}

// ---------------- K1c: per-block partial column sums ------------------------
// 256 blocks x 256 threads; block b sums 32 rows, thread c owns column c.
__global__ void k_colsum(const float* __restrict__ src, const float* __restrict__ tgt,
                         float* __restrict__ colpart) {
  int b = blockIdx.x, c = threadIdx.x;
  const float* base = (b < 128) ? (src + (size_t)b * 32 * DIM)
                                : (tgt + (size_t)(b - 128) * 32 * DIM);
  float s = 0.f;
#pragma unroll 8
  for (int r = 0; r < 32; ++r) s += base[(size_t)r * DIM + c];
  colpart[b * DIM + c] = s;
}

// ---------------- K1d: bandwidth scalar + zero the accumulator --------------
__global__ void k_scal(const float* __restrict__ sq, const float* __restrict__ colpart,
                       float* __restrict__ scal) {
  int c = threadIdx.x, lane = c & 63, w = c >> 6;
  float vs = 0.f;
  for (int b = 0; b < 256; ++b) vs += colpart[b * DIM + c];
  float vn = vs * vs;
  float ss = 0.f;
  for (int k = 0; k < 32; ++k) ss += sq[k * 256 + c];
#pragma unroll
  for (int off = 32; off > 0; off >>= 1) {
    vn += __shfl_down(vn, off);
    ss += __shfl_down(ss, off);
  }
  __shared__ float rv[4], rs[4];
  if (lane == 0) { rv[w] = vn; rs[w] = ss; }
  __syncthreads();
  if (c == 0) {
    double S  = (double)rs[0] + rs[1] + rs[2] + rs[3];
    double VN = (double)rv[0] + rv[1] + rv[2] + rv[3];
    double suml2 = 2.0 * (double)NROW * S - 2.0 * VN;
    double bw = suml2 / ((double)NROW * NROW - NROW) / 4.0; // / KERNEL_MUL^(5/2)
    // t = exp(-l2/(16*bw)) = exp2(-l2 * log2(e)/(16*bw))
    scal[0] = (float)(1.4426950408889634 / (bw * 16.0));
    scal[1] = 0.f; // global accumulator
  }
}

// ---------------- K2: fused X*X^T + multi-RBF epilogue + signed reduce ------
// 2080 blocks (upper-tri 128x128 tiles) x 256 threads (4 waves, 2x2 of 64x64).
__global__ __launch_bounds__(256, 3) void k_main(const u16* __restrict__ Xb,
                                                 const float* __restrict__ sq,
                                                 const float* __restrict__ scal,
                                                 float* __restrict__ accp) {
  __shared__ __align__(16) u16 As[128 * 64];
  __shared__ __align__(16) u16 Bs[128 * 64];
  __shared__ float red[4];

  // linear triangle index -> (bi, bj), bj >= bi
  int bi = 0, rem = blockIdx.x;
  while (rem >= TILES - bi) { rem -= TILES - bi; ++bi; }
  int bj = bi + rem;

  int tid = threadIdx.x;
  int w = tid >> 6, lane = tid & 63;
  int wi = w >> 1, wj = w & 1;

  f32x4 acc[4][4];
#pragma unroll
  for (int a = 0; a < 4; ++a)
#pragma unroll
    for (int b = 0; b < 4; ++b) acc[a][b] = (f32x4){0.f, 0.f, 0.f, 0.f};

  const int rowA0 = bi * 128;
  const int rowB0 = bj * 128;
  const int lrow = lane >> 3;        // 0..7 within 8-row group
  const int scol = (lane & 7) * 8;   // 0..56, 8 bf16 = 16B per lane

  for (int k0 = 0; k0 < DIM; k0 += 64) {
    __syncthreads(); // protect LDS from previous iteration's readers
#pragma unroll
    for (int q = 0; q < 4; ++q) {
      int r = w * 32 + q * 8; // wave-uniform row base within tile
      __builtin_amdgcn_global_load_lds(
          (const __attribute__((address_space(1))) void*)(Xb + (size_t)(rowA0 + r + lrow) * DIM + k0 + scol),
          (__attribute__((address_space(3))) void*)(As + r * 64), 16, 0, 0);
      __builtin_amdgcn_global_load_lds(
          (const __attribute__((address_space(1))) void*)(Xb + (size_t)(rowB0 + r + lrow) * DIM + k0 + scol),
          (__attribute__((address_space(3))) void*)(Bs + r * 64), 16, 0, 0);
    }
    __syncthreads(); // drains vmcnt(0): staged data visible

#pragma unroll
    for (int ks = 0; ks < 2; ++ks) {
      bf16x8 af[4], bf[4];
#pragma unroll
      for (int mi = 0; mi < 4; ++mi)
        af[mi] = *(const bf16x8*)&As[(wi * 64 + mi * 16 + (lane & 15)) * 64 + ks * 32 + (lane >> 4) * 8];
#pragma unroll
      for (int ni = 0; ni < 4; ++ni)
        bf[ni] = *(const bf16x8*)&Bs[(wj * 64 + ni * 16 + (lane & 15)) * 64 + ks * 32 + (lane >> 4) * 8];
#pragma unroll
      for (int mi = 0; mi < 4; ++mi)
#pragma unroll
        for (int ni = 0; ni < 4; ++ni)
          acc[mi][ni] = __builtin_amdgcn_mfma_f32_16x16x32_bf16(af[mi], bf[ni], acc[mi][ni], 0, 0, 0);
    }
  }

  // Epilogue: l2 -> t + t^2 + t^4 + t^8 + t^16, signed sum.
  // C/D layout: col = lane&15, row = (lane>>4)*4 + reg  [m89/m91 verified]
  float c4 = scal[0];
  float wgt = ((bi < 32) == (bj < 32)) ? 1.f : -1.f; // quadrant sign s_i*s_j
  if (bi != bj) wgt *= 2.f;                          // symmetry: count (j,i) too
  int ib = bi * 128 + wi * 64 + (lane >> 4) * 4;
  int jb = bj * 128 + wj * 64 + (lane & 15);
  f32x4 sqi[4];
#pragma unroll
  for (int mi = 0; mi < 4; ++mi) sqi[mi] = *(const f32x4*)(sq + ib + mi * 16);
  float lsum = 0.f;
#pragma unroll
  for (int ni = 0; ni < 4; ++ni) {
    float sqj = sq[jb + ni * 16];
#pragma unroll
    for (int mi = 0; mi < 4; ++mi) {
#pragma unroll
      for (int r = 0; r < 4; ++r) {
        float l2 = sqi[mi][r] + sqj - 2.f * acc[mi][ni][r];
        float t  = fast_exp2(-l2 * c4);
        float t2 = t * t, t4 = t2 * t2, t8 = t4 * t4, t16 = t8 * t8;
        lsum += t + t2 + t4 + t8 + t16;
      }
    }
  }
#pragma unroll
  for (int off = 32; off > 0; off >>= 1) lsum += __shfl_down(lsum, off);
  if (lane == 0) red[w] = lsum;
  __syncthreads();
  if (tid == 0) atomicAdd(accp, wgt * (red[0] + red[1] + red[2] + red[3]));
}

// ---------------- K3: finalize ----------------------------------------------
__global__ void k_fin(const float* __restrict__ scal, float* __restrict__ out) {
  if (threadIdx.x == 0) out[0] = scal[1] / 16777216.f; // / 4096^2
}

extern "C" void kernel_launch(void* const* d_in, const int* in_sizes, int n_in,
                              void* d_out, int out_size, void* d_ws, size_t ws_size,
                              hipStream_t stream) {
  const float* src = (const float*)d_in[0];
  const float* tgt = (const float*)d_in[1];
  char* ws = (char*)d_ws;
  u16* Xb = (u16*)ws;                                            // 4 MiB bf16 matrix
  float* sq = (float*)(ws + (size_t)NROW * DIM * 2);             // 32 KiB row |x|^2
  float* colpart = (float*)(ws + (size_t)NROW * DIM * 2 + NROW * 4);          // 256 KiB
  float* scal = (float*)(ws + (size_t)NROW * DIM * 2 + NROW * 4 + 256 * 256 * 4);
  float* out = (float*)d_out;

  k_prep<<<NROW / 4, 256, 0, stream>>>(src, tgt, Xb, sq);
  k_colsum<<<256, 256, 0, stream>>>(src, tgt, colpart);
  k_scal<<<1, 256, 0, stream>>>(sq, colpart, scal);
  k_main<<<NBLK, 256, 0, stream>>>(Xb, sq, scal, scal + 1);
  k_fin<<<1, 64, 0, stream>>>(scal, out);
}